// Round 5
// baseline (280.705 us; speedup 1.0000x reference)
//
#include <hip/hip_runtime.h>
#include <hip/hip_bf16.h>
#include <math.h>

typedef __attribute__((ext_vector_type(8))) short bf16x8;
typedef __attribute__((ext_vector_type(4))) float f32x4;

#define N_B  2
#define CIN  128
#define COUT 128
#define T_   16
#define H_   64
#define W_   64
#define FANIN 3456

// ---- workspace byte offsets ----
#define OFF_WMAX   0          // 128 f32
#define OFF_SMAX   512        // 2 f32
#define OFF_SNORM  1024       // 4096 f32
#define OFF_WSQ    20480      // 16384 f32
#define OFF_DEMOD  86016      // 4096 f32
#define OFF_APACK  102400     // 442368 ushort (884,736 B)  [tap27][c4][m8][lane64][j8]
#define OFF_ZERO   1048576    // 16384 B zero page (below xmt)
#define OFF_XMT    2097152    // 16,777,216 ushort (33.55 MB) [n][t][h][cc4][w64][cin32] bf16
#define ZOFF       (-524288)  // (OFF_ZERO-OFF_XMT)/2 : zero page as ushort-offset from xmt

// ---------- prep kernels ----------
__global__ __launch_bounds__(256) void k_zero(uint4* __restrict__ zp) {
    #pragma unroll
    for (int k = 0; k < 4; ++k)
        zp[threadIdx.x + k * 256] = make_uint4(0u, 0u, 0u, 0u);
}

__global__ __launch_bounds__(256) void k_wmax(const float* __restrict__ w,
                                              float* __restrict__ wmax) {
    int o = blockIdx.x;
    const float* p = w + (size_t)o * FANIN;
    float m = 0.f;
    for (int i = threadIdx.x; i < FANIN; i += 256) m = fmaxf(m, fabsf(p[i]));
    __shared__ float red[256];
    red[threadIdx.x] = m; __syncthreads();
    for (int s = 128; s > 0; s >>= 1) {
        if (threadIdx.x < s) red[threadIdx.x] = fmaxf(red[threadIdx.x], red[threadIdx.x + s]);
        __syncthreads();
    }
    if (threadIdx.x == 0) wmax[o] = red[0];
}

__global__ __launch_bounds__(256) void k_smax(const float* __restrict__ s,
                                              float* __restrict__ smax) {
    int n = blockIdx.x;
    const float* p = s + (size_t)n * CIN * T_;
    float m = 0.f;
    for (int i = threadIdx.x; i < CIN * T_; i += 256) m = fmaxf(m, fabsf(p[i]));
    __shared__ float red[256];
    red[threadIdx.x] = m; __syncthreads();
    for (int q = 128; q > 0; q >>= 1) {
        if (threadIdx.x < q) red[threadIdx.x] = fmaxf(red[threadIdx.x], red[threadIdx.x + q]);
        __syncthreads();
    }
    if (threadIdx.x == 0) smax[n] = red[0];
}

__global__ __launch_bounds__(256) void k_snorm(const float* __restrict__ style,
                                               const float* __restrict__ smax,
                                               float* __restrict__ snorm) {
    int idx = blockIdx.x * 256 + threadIdx.x;
    if (idx < N_B * CIN * T_) {
        int n = idx / (CIN * T_);
        snorm[idx] = style[idx] / smax[n];
    }
}

// normalize weight (fp32), pack bf16 into MFMA A-frag order, compute wsq[o][i]
__global__ __launch_bounds__(128) void k_wpack(const float* __restrict__ w,
                                               const float* __restrict__ wmax,
                                               ushort* __restrict__ apack,
                                               float* __restrict__ wsq) {
    int o = blockIdx.x, i = threadIdx.x;
    float inv = 1.0f / (wmax[o] * sqrtf((float)FANIN));
    const float* p = w + ((size_t)o * CIN + i) * 27;
    int c = i >> 5, ii = i & 31;
    int lane = (o & 15) + ((ii >> 3) << 4);   // A: row=l&15, k=(l>>4)*8+j
    int j = ii & 7;
    int m = o >> 4;
    size_t base = (((size_t)c * 8 + m) * 64 + lane) * 8 + j;
    float sq = 0.f;
    #pragma unroll
    for (int tap = 0; tap < 27; tap++) {
        float wn = p[tap] * inv;
        sq = fmaf(wn, wn, sq);
        __hip_bfloat16 hb = __float2bfloat16(wn);
        apack[base + (size_t)tap * 16384] = *(ushort*)&hb;
    }
    wsq[o * CIN + i] = sq;
}

__global__ __launch_bounds__(128) void k_demod(const float* __restrict__ wsq,
                                               const float* __restrict__ snorm,
                                               float* __restrict__ demod) {
    int nt = blockIdx.x;
    int n = nt / T_, t = nt % T_;
    __shared__ float s2[CIN];
    int tid = threadIdx.x;
    float sv = snorm[(n * CIN + tid) * T_ + t];
    s2[tid] = sv * sv;
    __syncthreads();
    const float* wq = wsq + tid * CIN;   // o = tid
    float d = 0.f;
    for (int i = 0; i < CIN; i++) d = fmaf(wq[i], s2[i], d);
    demod[(n * COUT + tid) * T_ + t] = 1.0f / sqrtf(d + 1e-8f);
}

// transpose x -> xmt[n][t][h][cc4][w64][cin32] bf16, style-modulated
__global__ __launch_bounds__(256) void k_xmt(const float* __restrict__ x,
                                             const float* __restrict__ snorm,
                                             ushort* __restrict__ xmt) {
    __shared__ float lds[CIN * 65];
    int bid = blockIdx.x;
    int h = bid & 63, t = (bid >> 6) & 15, n = bid >> 10;
    int tid = threadIdx.x;
    int wl = tid & 63, cq = tid >> 6;
    for (int pass = 0; pass < 32; pass++) {
        int ci = pass * 4 + cq;
        float s = snorm[(n * CIN + ci) * T_ + t];
        float v = x[(((size_t)(n * CIN + ci) * T_ + t) * H_ + h) * W_ + wl] * s;
        lds[ci * 65 + wl] = v;
    }
    __syncthreads();
    int ci2 = tid & 63, wq = tid >> 6;   // ci2 = cin-pair index 0..63
    uint* dst = (uint*)xmt;
    for (int pass = 0; pass < 16; pass++) {
        int w = pass * 4 + wq;
        float f0 = lds[(2 * ci2) * 65 + w];
        float f1 = lds[(2 * ci2 + 1) * 65 + w];
        __hip_bfloat16 h0 = __float2bfloat16(f0);
        __hip_bfloat16 h1 = __float2bfloat16(f1);
        uint pk = (uint)(*(ushort*)&h0) | ((uint)(*(ushort*)&h1) << 16);
        // [n][t][h][cc4][w64][cin32] as uints: ((((n*16+t)*64+h)*4 + cc)*64 + w)*16 + pair
        dst[(size_t)((((n * 16 + t) * 64 + h) * 4 + (ci2 >> 4)) * 64 + w) * 16 + (ci2 & 15)] = pk;
    }
}

// ---------- main MFMA conv ----------
// grid: 512 blocks = n(2) * t(16) * h4(16); block = 256 thr = 4 waves
// block tile: 128 Cout x (4h x 64w); wave: 64 Cout x (2h x 64w) -> 4m x 8n frags
// Staging: global_load_lds, FULLY CONVERGENT — every slot, every lane, every
// wave issues; OOB-halo / padding lanes read from the zero page instead.
#define NSLOT 19
__global__ __launch_bounds__(256, 2) void k_conv(const ushort* __restrict__ xmt,
                                                 const ushort* __restrict__ apack,
                                                 const float* __restrict__ demod,
                                                 const float* __restrict__ bias,
                                                 float* __restrict__ out) {
    __shared__ ushort __attribute__((aligned(16))) xs[38912];   // 4864 granules * 16B = 77824 B

    int bid = blockIdx.x;
    int h4 = bid & 15, t = (bid >> 4) & 15, n = bid >> 8;
    int hbase = h4 * 4;
    int tid = threadIdx.x;
    int lane = tid & 63;
    int wid = tid >> 6;
    int mrow = wid & 1;    // cout half (64)
    int hp = wid >> 1;     // h pair (rows 2*hp, 2*hp+1)
    int lw = lane & 15, lg = lane >> 4;

    // ---- chunk-invariant staging offsets (signed; ZOFF = zero page) ----
    int goff[NSLOT];
    #pragma unroll
    for (int k = 0; k < NSLOT; ++k) {
        int idx = tid + (k << 8);
        int off = ZOFF;
        if (idx < 4752) {
            int g = idx & 3;
            int r = idx >> 2;
            int w = r % 66;
            int q = r / 66;
            int hh = q % 6, tz = q / 6;
            int gt = t + tz - 1, gh = hbase + hh - 1, gw = w - 1;
            if ((unsigned)gt < T_ && (unsigned)gh < H_ && (unsigned)gw < W_)
                off = (((n * 16 + gt) * 64 + gh) * 4) * 2048 + (gw * 32 + g * 8);
        }
        goff[k] = off;
    }

#define STAGE(cc) do { \
    _Pragma("unroll") \
    for (int k = 0; k < NSLOT; ++k) \
        __builtin_amdgcn_global_load_lds( \
            (const __attribute__((address_space(1))) void*)(xmt + goff[k] + (cc) * 2048), \
            (__attribute__((address_space(3))) void*)((char*)xs + (size_t)(tid + (k << 8)) * 16), \
            16, 0, 0); \
} while (0)

    f32x4 acc[4][8];
    #pragma unroll
    for (int i = 0; i < 4; i++)
        #pragma unroll
        for (int jn = 0; jn < 8; jn++)
            acc[i][jn] = (f32x4){0.f, 0.f, 0.f, 0.f};

    STAGE(0);
    __syncthreads();

    for (int c = 0; c < 4; ++c) {     // cin chunks of 32
        const ushort* apc = apack + (c * 4096 + mrow * 2048 + lane * 8);
        #pragma unroll
        for (int tz = 0; tz < 3; tz++) {
            #pragma unroll
            for (int dy = 0; dy < 3; dy++) {
                int row0 = (tz * 6 + hp * 2 + dy) * 66;   // rl = 0
                #pragma unroll
                for (int dx = 0; dx < 3; dx++) {
                    int tap = (tz * 3 + dy) * 3 + dx;
                    const ushort* ap = apc + tap * 16384;
                    bf16x8 a[4], b[8];
                    a[0] = *(const bf16x8*)(ap);
                    a[1] = *(const bf16x8*)(ap + 512);
                    a[2] = *(const bf16x8*)(ap + 1024);
                    a[3] = *(const bf16x8*)(ap + 1536);
                    #pragma unroll
                    for (int nb = 0; nb < 8; nb++) {
                        int rowb = row0 + (nb >> 2) * 66;
                        int ws = nb & 3;
                        int gran = (rowb + ws * 16 + lw + dx) * 4 + lg;
                        b[nb] = *(const bf16x8*)(&xs[(size_t)gran * 8]);
                    }
                    #pragma unroll
                    for (int mi = 0; mi < 4; mi++)
                        #pragma unroll
                        for (int nb = 0; nb < 8; nb++)
                            acc[mi][nb] = __builtin_amdgcn_mfma_f32_16x16x32_bf16(
                                a[mi], b[nb], acc[mi][nb], 0, 0, 0);
                }
            }
        }
        if (c < 3) {
            __syncthreads();   // all waves done reading chunk c
            STAGE(c + 1);
            __syncthreads();   // glds complete (vmcnt drained) + visible
        }
    }

    // epilogue: C layout col=lane&15 (w), row=(lane>>4)*4+reg (cout)
    int h0 = hbase + hp * 2;
    #pragma unroll
    for (int mi = 0; mi < 4; mi++) {
        #pragma unroll
        for (int r = 0; r < 4; r++) {
            int o = mrow * 64 + mi * 16 + lg * 4 + r;
            float d = demod[(n * COUT + o) * T_ + t];
            float bv = bias[o];
            #pragma unroll
            for (int nb = 0; nb < 8; nb++) {
                int rl = nb >> 2, ws = nb & 3;
                float z = fmaf(acc[mi][nb][r], d, bv);
                z = (z >= 0.f ? z : 0.2f * z) * 1.41421356237309515f;
                out[(((size_t)(n * COUT + o) * T_ + t) * H_ + h0 + rl) * W_ + ws * 16 + lw] = z;
            }
        }
    }
#undef STAGE
}

extern "C" void kernel_launch(void* const* d_in, const int* in_sizes, int n_in,
                              void* d_out, int out_size, void* d_ws, size_t ws_size,
                              hipStream_t stream) {
    const float* x      = (const float*)d_in[0];
    const float* weight = (const float*)d_in[1];
    const float* style  = (const float*)d_in[2];
    const float* bias   = (const float*)d_in[3];
    float* out = (float*)d_out;

    char* ws = (char*)d_ws;
    float*  wmax  = (float*)(ws + OFF_WMAX);
    float*  smax  = (float*)(ws + OFF_SMAX);
    float*  snorm = (float*)(ws + OFF_SNORM);
    float*  wsq   = (float*)(ws + OFF_WSQ);
    float*  demod = (float*)(ws + OFF_DEMOD);
    uint4*  zpage = (uint4*)(ws + OFF_ZERO);
    ushort* apack = (ushort*)(ws + OFF_APACK);
    ushort* xmt   = (ushort*)(ws + OFF_XMT);

    k_zero <<<1, 256, 0, stream>>>(zpage);
    k_wmax <<<COUT, 256, 0, stream>>>(weight, wmax);
    k_smax <<<N_B, 256, 0, stream>>>(style, smax);
    k_snorm<<<(N_B * CIN * T_ + 255) / 256, 256, 0, stream>>>(style, smax, snorm);
    k_wpack<<<COUT, 128, 0, stream>>>(weight, wmax, apack, wsq);
    k_demod<<<N_B * T_, 128, 0, stream>>>(wsq, snorm, demod);
    k_xmt  <<<N_B * T_ * H_, 256, 0, stream>>>(x, snorm, xmt);

    k_conv<<<N_B * T_ * (H_ / 4), 256, 0, stream>>>(xmt, apack, demod, bias, out);
}

// Round 6
// 136.094 us; speedup vs baseline: 2.0626x; 2.0626x over previous
//
#include <hip/hip_runtime.h>
#include <hip/hip_bf16.h>
#include <math.h>

typedef __attribute__((ext_vector_type(8))) short bf16x8;
typedef __attribute__((ext_vector_type(4))) float f32x4;

#define N_B  2
#define CIN  128
#define COUT 128
#define T_   16
#define H_   64
#define W_   64
#define FANIN 3456

// ---- workspace byte offsets ----
#define OFF_WMAX   0          // 128 f32
#define OFF_SMAX   512        // 2 f32
#define OFF_SNORM  1024       // 4096 f32
#define OFF_WSQ    20480      // 16384 f32
#define OFF_DEMOD  86016      // 4096 f32
#define OFF_APACK  102400     // 442368 ushort (884,736 B)  [tap27][c4][m8][lane64][j8]
#define OFF_XMT    2097152    // 16,777,216 ushort (33.55 MB) [n][t][h][w][cin] bf16

// ---------- prep kernels ----------
__global__ __launch_bounds__(256) void k_wmax(const float* __restrict__ w,
                                              float* __restrict__ wmax) {
    int o = blockIdx.x;
    const float* p = w + (size_t)o * FANIN;
    float m = 0.f;
    for (int i = threadIdx.x; i < FANIN; i += 256) m = fmaxf(m, fabsf(p[i]));
    __shared__ float red[256];
    red[threadIdx.x] = m; __syncthreads();
    for (int s = 128; s > 0; s >>= 1) {
        if (threadIdx.x < s) red[threadIdx.x] = fmaxf(red[threadIdx.x], red[threadIdx.x + s]);
        __syncthreads();
    }
    if (threadIdx.x == 0) wmax[o] = red[0];
}

__global__ __launch_bounds__(256) void k_smax(const float* __restrict__ s,
                                              float* __restrict__ smax) {
    int n = blockIdx.x;
    const float* p = s + (size_t)n * CIN * T_;
    float m = 0.f;
    for (int i = threadIdx.x; i < CIN * T_; i += 256) m = fmaxf(m, fabsf(p[i]));
    __shared__ float red[256];
    red[threadIdx.x] = m; __syncthreads();
    for (int q = 128; q > 0; q >>= 1) {
        if (threadIdx.x < q) red[threadIdx.x] = fmaxf(red[threadIdx.x], red[threadIdx.x + q]);
        __syncthreads();
    }
    if (threadIdx.x == 0) smax[n] = red[0];
}

__global__ __launch_bounds__(256) void k_snorm(const float* __restrict__ style,
                                               const float* __restrict__ smax,
                                               float* __restrict__ snorm) {
    int idx = blockIdx.x * 256 + threadIdx.x;
    if (idx < N_B * CIN * T_) {
        int n = idx / (CIN * T_);
        snorm[idx] = style[idx] / smax[n];
    }
}

// normalize weight (fp32), pack bf16 into MFMA A-frag order, compute wsq[o][i]
__global__ __launch_bounds__(128) void k_wpack(const float* __restrict__ w,
                                               const float* __restrict__ wmax,
                                               ushort* __restrict__ apack,
                                               float* __restrict__ wsq) {
    int o = blockIdx.x, i = threadIdx.x;
    float inv = 1.0f / (wmax[o] * sqrtf((float)FANIN));
    const float* p = w + ((size_t)o * CIN + i) * 27;
    int c = i >> 5, ii = i & 31;
    int lane = (o & 15) + ((ii >> 3) << 4);   // A: row=l&15, k=(l>>4)*8+j
    int j = ii & 7;
    int m = o >> 4;
    size_t base = (((size_t)c * 8 + m) * 64 + lane) * 8 + j;
    float sq = 0.f;
    #pragma unroll
    for (int tap = 0; tap < 27; tap++) {
        float wn = p[tap] * inv;
        sq = fmaf(wn, wn, sq);
        __hip_bfloat16 hb = __float2bfloat16(wn);
        apack[base + (size_t)tap * 16384] = *(ushort*)&hb;
    }
    wsq[o * CIN + i] = sq;
}

__global__ __launch_bounds__(128) void k_demod(const float* __restrict__ wsq,
                                               const float* __restrict__ snorm,
                                               float* __restrict__ demod) {
    int nt = blockIdx.x;
    int n = nt / T_, t = nt % T_;
    __shared__ float s2[CIN];
    int tid = threadIdx.x;
    float sv = snorm[(n * CIN + tid) * T_ + t];
    s2[tid] = sv * sv;
    __syncthreads();
    const float* wq = wsq + tid * CIN;   // o = tid
    float d = 0.f;
    for (int i = 0; i < CIN; i++) d = fmaf(wq[i], s2[i], d);
    demod[(n * COUT + tid) * T_ + t] = 1.0f / sqrtf(d + 1e-8f);
}

// transpose x -> xmt[n][t][h][w][cin] bf16, style-modulated
__global__ __launch_bounds__(256) void k_xmt(const float* __restrict__ x,
                                             const float* __restrict__ snorm,
                                             ushort* __restrict__ xmt) {
    __shared__ float lds[CIN * 65];
    int bid = blockIdx.x;
    int h = bid & 63, t = (bid >> 6) & 15, n = bid >> 10;
    int tid = threadIdx.x;
    int wl = tid & 63, cq = tid >> 6;
    for (int pass = 0; pass < 32; pass++) {
        int ci = pass * 4 + cq;
        float s = snorm[(n * CIN + ci) * T_ + t];
        float v = x[(((size_t)(n * CIN + ci) * T_ + t) * H_ + h) * W_ + wl] * s;
        lds[ci * 65 + wl] = v;
    }
    __syncthreads();
    int ci2 = tid & 63, wq = tid >> 6;
    uint* dst = (uint*)xmt;
    for (int pass = 0; pass < 16; pass++) {
        int w = pass * 4 + wq;
        float f0 = lds[(2 * ci2) * 65 + w];
        float f1 = lds[(2 * ci2 + 1) * 65 + w];
        __hip_bfloat16 h0 = __float2bfloat16(f0);
        __hip_bfloat16 h1 = __float2bfloat16(f1);
        uint pk = (uint)(*(ushort*)&h0) | ((uint)(*(ushort*)&h1) << 16);
        dst[((((size_t)(n * T_ + t) * H_ + h) * W_ + w)) * 64 + ci2] = pk;
    }
}

// ---------- main MFMA conv ----------
// grid: 1024 blocks = n(2) * t(16) * h2(32); block = 256 thr = 4 waves
// block tile: 128 Cout x (2h x 64w); wave: 64 Cout x (1h x 64w)
// A-operand ping-pong pipeline at (tz,dy)-group granularity: issue next
// group's 12 A-loads, sched_barrier(0), then current group's 48 MFMAs.
__global__ __launch_bounds__(256, 2) void k_conv(const ushort* __restrict__ xmt,
                                                 const ushort* __restrict__ apack,
                                                 const float* __restrict__ demod,
                                                 const float* __restrict__ bias,
                                                 float* __restrict__ out) {
    // xs[t'3][h'4][g4][w66] granules of 8 bf16 (16B)
    __shared__ ushort __attribute__((aligned(16))) xs[25344];   // 50688 B

    int bid = blockIdx.x;
    int h2 = bid & 31, t = (bid >> 5) & 15, n = bid >> 9;
    int hbase = h2 * 2;
    int tid = threadIdx.x;
    int lane = tid & 63;
    int wid = tid >> 6;
    int mrow = wid & 1;    // cout half (64)
    int hrow = wid >> 1;   // h row (0/1)

    // ---- chunk-invariant staging offsets (13 granules/thread) ----
    uint goff[13];     // element offset into xmt (for chunk c add c*32)
    uint loff[13];     // byte offset into xs; 0xFFFFFFFF = no slot
    uint vmask = 0;    // bit k set -> in-bounds (load), clear -> zero-fill
    #pragma unroll
    for (int k = 0; k < 13; ++k) {
        int idx = tid + (k << 8);
        goff[k] = 0u;
        if (idx < 3168) {
            int g = idx & 3;
            int r = idx >> 2;
            int w = r % 66;
            int q = r / 66;
            int hh = q & 3, tz = q >> 2;
            int gt = t + tz - 1, gh = hbase + hh - 1, gw = w - 1;
            if ((unsigned)gt < T_ && (unsigned)gh < H_ && (unsigned)gw < W_) {
                goff[k] = (uint)((((n * T_ + gt) * H_ + gh) * W_ + gw) * CIN + g * 8);
                vmask |= (1u << k);
            }
            loff[k] = (uint)(((((tz * 4 + hh) * 4) + g) * 66 + w) * 16);
        } else {
            loff[k] = 0xFFFFFFFFu;
        }
    }

    f32x4 acc[4][4];
    #pragma unroll
    for (int i = 0; i < 4; i++)
        #pragma unroll
        for (int jn = 0; jn < 4; jn++)
            acc[i][jn] = (f32x4){0.f, 0.f, 0.f, 0.f};

    bf16x8 Abank0[12], Abank1[12];

#define LOADA(BANK, G) do { \
    const ushort* apg_ = apc + (G) * 3 * 16384; \
    _Pragma("unroll") \
    for (int dx_ = 0; dx_ < 3; ++dx_) { \
        _Pragma("unroll") \
        for (int mi_ = 0; mi_ < 4; ++mi_) \
            BANK[dx_ * 4 + mi_] = *(const bf16x8*)(apg_ + dx_ * 16384 + mi_ * 512); \
    } \
} while (0)

#define GROUPC(BANK, G) do { \
    const int tz_ = (G) / 3, dy_ = (G) % 3; \
    const ushort* bb_ = &xs[(((tz_ * 4 + hrow + dy_) * 4 + (lane >> 4)) * 66 + (lane & 15)) * 8]; \
    _Pragma("unroll") \
    for (int dx_ = 0; dx_ < 3; ++dx_) { \
        bf16x8 b0_ = *(const bf16x8*)(bb_ + dx_ * 8); \
        bf16x8 b1_ = *(const bf16x8*)(bb_ + dx_ * 8 + 128); \
        bf16x8 b2_ = *(const bf16x8*)(bb_ + dx_ * 8 + 256); \
        bf16x8 b3_ = *(const bf16x8*)(bb_ + dx_ * 8 + 384); \
        _Pragma("unroll") \
        for (int mi_ = 0; mi_ < 4; ++mi_) { \
            acc[mi_][0] = __builtin_amdgcn_mfma_f32_16x16x32_bf16(BANK[dx_*4+mi_], b0_, acc[mi_][0], 0, 0, 0); \
            acc[mi_][1] = __builtin_amdgcn_mfma_f32_16x16x32_bf16(BANK[dx_*4+mi_], b1_, acc[mi_][1], 0, 0, 0); \
            acc[mi_][2] = __builtin_amdgcn_mfma_f32_16x16x32_bf16(BANK[dx_*4+mi_], b2_, acc[mi_][2], 0, 0, 0); \
            acc[mi_][3] = __builtin_amdgcn_mfma_f32_16x16x32_bf16(BANK[dx_*4+mi_], b3_, acc[mi_][3], 0, 0, 0); \
        } \
    } \
} while (0)

    for (int c = 0; c < 4; ++c) {     // cin chunks of 32
        __syncthreads();   // waves done reading previous chunk
        // serial stage of chunk c: 13 loads then 13 ds_writes
        {
            uint4 pv[13];
            #pragma unroll
            for (int k = 0; k < 13; ++k) {
                uint4 v = make_uint4(0u, 0u, 0u, 0u);
                if ((vmask >> k) & 1u) v = *(const uint4*)(xmt + goff[k] + c * 32);
                pv[k] = v;
            }
            #pragma unroll
            for (int k = 0; k < 13; ++k)
                if (loff[k] != 0xFFFFFFFFu) *(uint4*)((char*)&xs[0] + loff[k]) = pv[k];
        }
        __syncthreads();

        const ushort* apc = apack + (c * 4096 + mrow * 2048 + lane * 8);

        LOADA(Abank0, 0);
        LOADA(Abank1, 1); __builtin_amdgcn_sched_barrier(0); GROUPC(Abank0, 0);
        LOADA(Abank0, 2); __builtin_amdgcn_sched_barrier(0); GROUPC(Abank1, 1);
        LOADA(Abank1, 3); __builtin_amdgcn_sched_barrier(0); GROUPC(Abank0, 2);
        LOADA(Abank0, 4); __builtin_amdgcn_sched_barrier(0); GROUPC(Abank1, 3);
        LOADA(Abank1, 5); __builtin_amdgcn_sched_barrier(0); GROUPC(Abank0, 4);
        LOADA(Abank0, 6); __builtin_amdgcn_sched_barrier(0); GROUPC(Abank1, 5);
        LOADA(Abank1, 7); __builtin_amdgcn_sched_barrier(0); GROUPC(Abank0, 6);
        LOADA(Abank0, 8); __builtin_amdgcn_sched_barrier(0); GROUPC(Abank1, 7);
        GROUPC(Abank0, 8);
    }
#undef LOADA
#undef GROUPC

    // epilogue: C layout col=lane&15 (w), row=(lane>>4)*4+reg (cout)
    int h = hbase + hrow;
    #pragma unroll
    for (int mi = 0; mi < 4; mi++) {
        #pragma unroll
        for (int r = 0; r < 4; r++) {
            int o = mrow * 64 + mi * 16 + (lane >> 4) * 4 + r;
            float d = demod[(n * COUT + o) * T_ + t];
            float bv = bias[o];
            #pragma unroll
            for (int nb = 0; nb < 4; nb++) {
                float z = fmaf(acc[mi][nb][r], d, bv);
                z = (z >= 0.f ? z : 0.2f * z) * 1.41421356237309515f;
                out[(((size_t)(n * COUT + o) * T_ + t) * H_ + h) * W_ + nb * 16 + (lane & 15)] = z;
            }
        }
    }
}

extern "C" void kernel_launch(void* const* d_in, const int* in_sizes, int n_in,
                              void* d_out, int out_size, void* d_ws, size_t ws_size,
                              hipStream_t stream) {
    const float* x      = (const float*)d_in[0];
    const float* weight = (const float*)d_in[1];
    const float* style  = (const float*)d_in[2];
    const float* bias   = (const float*)d_in[3];
    float* out = (float*)d_out;

    char* ws = (char*)d_ws;
    float*  wmax  = (float*)(ws + OFF_WMAX);
    float*  smax  = (float*)(ws + OFF_SMAX);
    float*  snorm = (float*)(ws + OFF_SNORM);
    float*  wsq   = (float*)(ws + OFF_WSQ);
    float*  demod = (float*)(ws + OFF_DEMOD);
    ushort* apack = (ushort*)(ws + OFF_APACK);
    ushort* xmt   = (ushort*)(ws + OFF_XMT);

    k_wmax <<<COUT, 256, 0, stream>>>(weight, wmax);
    k_smax <<<N_B, 256, 0, stream>>>(style, smax);
    k_snorm<<<(N_B * CIN * T_ + 255) / 256, 256, 0, stream>>>(style, smax, snorm);
    k_wpack<<<COUT, 128, 0, stream>>>(weight, wmax, apack, wsq);
    k_demod<<<N_B * T_, 128, 0, stream>>>(wsq, snorm, demod);
    k_xmt  <<<N_B * T_ * H_, 256, 0, stream>>>(x, snorm, xmt);

    k_conv<<<N_B * T_ * (H_ / 2), 256, 0, stream>>>(xmt, apack, demod, bias, out);
}